// Round 18
// baseline (259.198 us; speedup 1.0000x reference)
//
#include <hip/hip_runtime.h>
#include <hip/hip_bf16.h>

constexpr int DOUT = 256;

typedef __bf16 bf16x8 __attribute__((ext_vector_type(8)));
typedef float f32x4 __attribute__((ext_vector_type(4)));

__device__ inline float bf2f(ushort u) {
  return __uint_as_float((unsigned)u << 16);
}
__device__ inline ushort f2bf(float f) {
  unsigned b = __float_as_uint(f);
  return (ushort)((b + 0x7FFF + ((b >> 16) & 1)) >> 16);  // RNE
}
__device__ inline float bflo(int v) {
  return __uint_as_float((unsigned)v << 16);
}
__device__ inline float bfhi(int v) {
  return __uint_as_float((unsigned)v & 0xffff0000u);
}
__device__ inline int packbf(float a, float b) {
  return (int)((unsigned)f2bf(a) | ((unsigned)f2bf(b) << 16));
}

// async global->LDS, 16B/lane; LDS dest = wave-uniform base + lane*16
__device__ inline void gload_lds16(const ushort* g, ushort* l) {
  __builtin_amdgcn_global_load_lds(
      (const __attribute__((address_space(1))) unsigned int*)g,
      (__attribute__((address_space(3))) unsigned int*)l, 16, 0, 0);
}

// bijective XCD chunk swizzle (m204)
__device__ inline int xcd_swizzle(int bid, int nwg) {
  int q = nwg >> 3, r = nwg & 7;
  int xcd = bid & 7, idx = bid >> 3;
  return (xcd < r ? xcd * (q + 1) : r * (q + 1) + (xcd - r) * q) + idx;
}

// ---- fused counts: [0,Eb) degree, [Eb,Eb+nb) graph histogram, [..+1) hg=0 --
__global__ __launch_bounds__(256) void k_cnt(const int* __restrict__ edst,
                                             int* __restrict__ deg, int E, int Eb,
                                             const int* __restrict__ gid,
                                             int* __restrict__ gcnt, int n, int G,
                                             float* __restrict__ out_hg, int nb) {
  __shared__ int h[16];
  int b = blockIdx.x;
  if (b < Eb) {
    int t = b * 256 + threadIdx.x;
    if (t < E) atomicAdd(&deg[edst[t]], 1);
  } else if (b < Eb + nb) {
    b -= Eb;
    int t = threadIdx.x;
    if (t < G) h[t] = 0;
    __syncthreads();
    int i = b * 256 + t;
    if (i < n) atomicAdd(&h[gid[i]], 1);
    __syncthreads();
    if (t < G && h[t]) atomicAdd(&gcnt[t], h[t]);
  } else {
    int t = threadIdx.x;
    for (int i = t; i < G * 256; i += 256) out_hg[i] = 0.f;
  }
}

// ---------------- CSR build ----------------
__global__ __launch_bounds__(256) void k_scan1(const int* __restrict__ deg,
                                               int* __restrict__ part, int n) {
  int i = blockIdx.x * 256 + threadIdx.x;
  int v = (i < n) ? deg[i] : 0;
#pragma unroll
  for (int o = 32; o > 0; o >>= 1) v += __shfl_xor(v, o);
  __shared__ int s[4];
  int wave = threadIdx.x >> 6, lane = threadIdx.x & 63;
  if (lane == 0) s[wave] = v;
  __syncthreads();
  if (threadIdx.x == 0) part[blockIdx.x] = s[0] + s[1] + s[2] + s[3];
}

__global__ __launch_bounds__(256) void k_scan2(int* __restrict__ part, int nb) {
  __shared__ int s[256];
  int t = threadIdx.x;
  int v = (t < nb) ? part[t] : 0;
  s[t] = v;
  __syncthreads();
  for (int o = 1; o < 256; o <<= 1) {
    int u = (t >= o) ? s[t - o] : 0;
    __syncthreads();
    s[t] += u;
    __syncthreads();
  }
  int excl = (t == 0) ? 0 : s[t - 1];
  if (t < nb) part[t] = excl;
}

__global__ __launch_bounds__(256) void k_scan3(const int* __restrict__ deg,
                                               const int* __restrict__ part,
                                               int* __restrict__ rp,
                                               int* __restrict__ cur,
                                               float* __restrict__ dinv, int n) {
  __shared__ int s[256];
  int t = threadIdx.x;
  int i = blockIdx.x * 256 + t;
  int v = (i < n) ? deg[i] : 0;
  s[t] = v;
  __syncthreads();
  for (int o = 1; o < 256; o <<= 1) {
    int u = (t >= o) ? s[t - o] : 0;
    __syncthreads();
    s[t] += u;
    __syncthreads();
  }
  int incl = s[t];
  int excl = incl - v;
  int base = part[blockIdx.x];
  if (i < n) {
    rp[i] = base + excl;
    cur[i] = base + excl;
    dinv[i] = 1.0f / (float)v;
  }
  if (i == n - 1) rp[n] = base + incl;
}

__global__ __launch_bounds__(256) void k_fill(const int* __restrict__ src,
                                              const int* __restrict__ dst,
                                              int* __restrict__ cur,
                                              int* __restrict__ col, int E) {
  int e = blockIdx.x * 256 + threadIdx.x;
  if (e < E) {
    int p = atomicAdd(&cur[dst[e]], 1);
    col[p] = src[e];
  }
}

// ---------------- fused prep: feat cast + 3 weight transposes ----------------
__global__ __launch_bounds__(256) void k_prep(
    const float* __restrict__ feat, ushort* __restrict__ feat_bf,
    long long feat4, int castb,
    const float* __restrict__ Ws0, const float* __restrict__ Wn0,
    ushort* __restrict__ Wt0, int DIN0,
    const float* __restrict__ Ws1, const float* __restrict__ Wn1,
    ushort* __restrict__ Wt1,
    const float* __restrict__ Ws2, const float* __restrict__ Wn2,
    ushort* __restrict__ Wt2) {
  int b = blockIdx.x;
  if (b < castb) {
    long long t = (long long)b * 256 + threadIdx.x;
    if (t < feat4) {
      float4 v = *(const float4*)(feat + t * 4);
      ushort4 o;
      o.x = f2bf(v.x); o.y = f2bf(v.y); o.z = f2bf(v.z); o.w = f2bf(v.w);
      *(ushort4*)(feat_bf + t * 4) = o;
    }
    return;
  }
  b -= castb;
  const float *Ws, *Wn;
  ushort* Wt;
  int DIN;
  if (b < 2 * DIN0) {
    Ws = Ws0; Wn = Wn0; Wt = Wt0; DIN = DIN0;
  } else if (b < 2 * DIN0 + 512) {
    b -= 2 * DIN0; Ws = Ws1; Wn = Wn1; Wt = Wt1; DIN = 256;
  } else {
    b -= 2 * DIN0 + 512; Ws = Ws2; Wn = Wn2; Wt = Wt2; DIN = 256;
  }
  int t = b * 256 + threadIdx.x;
  int K = 2 * DIN;
  int nn = t & 255;
  int k = t >> 8;
  if (k < K) {
    const float* W = (k < DIN) ? (Ws + (size_t)k * 256)
                               : (Wn + (size_t)(k - DIN) * 256);
    Wt[(size_t)nn * K + k] = f2bf(W[nn]);
  }
}

// ---------------- CSR gather (bf16), 4 neighbor-groups per wave (R15) -------
template <int DIN>
__global__ __launch_bounds__(256) void k_gather(const ushort* __restrict__ h,
                                                const int* __restrict__ rp,
                                                const int* __restrict__ col,
                                                const float* __restrict__ dinv,
                                                ushort* __restrict__ agg, int n) {
  int wg = xcd_swizzle(blockIdx.x, gridDim.x);
  int wave = threadIdx.x >> 6, lane = threadIdx.x & 63;
  int node = wg * 4 + wave;
  if (node >= n) return;
  int beg = rp[node], end = rp[node + 1];
  float s = dinv[node];
  int quad = lane >> 4, sub = lane & 15;
  if constexpr (DIN == 256) {
    const ushort* base = h + sub * 16;
    float a[16] = {};
    int j = beg + quad;
    for (; j + 4 < end; j += 8) {
      const ushort* p0 = base + (size_t)col[j] * DIN;
      const ushort* p1 = base + (size_t)col[j + 4] * DIN;
      int4 u0 = *(const int4*)p0;
      int4 u1 = *(const int4*)(p0 + 8);
      int4 v0 = *(const int4*)p1;
      int4 v1 = *(const int4*)(p1 + 8);
      a[0] += bflo(u0.x) + bflo(v0.x);  a[1] += bfhi(u0.x) + bfhi(v0.x);
      a[2] += bflo(u0.y) + bflo(v0.y);  a[3] += bfhi(u0.y) + bfhi(v0.y);
      a[4] += bflo(u0.z) + bflo(v0.z);  a[5] += bfhi(u0.z) + bfhi(v0.z);
      a[6] += bflo(u0.w) + bflo(v0.w);  a[7] += bfhi(u0.w) + bfhi(v0.w);
      a[8] += bflo(u1.x) + bflo(v1.x);  a[9] += bfhi(u1.x) + bfhi(v1.x);
      a[10] += bflo(u1.y) + bflo(v1.y); a[11] += bfhi(u1.y) + bfhi(v1.y);
      a[12] += bflo(u1.z) + bflo(v1.z); a[13] += bfhi(u1.z) + bfhi(v1.z);
      a[14] += bflo(u1.w) + bflo(v1.w); a[15] += bfhi(u1.w) + bfhi(v1.w);
    }
    for (; j < end; j += 4) {
      const ushort* p0 = base + (size_t)col[j] * DIN;
      int4 u0 = *(const int4*)p0;
      int4 u1 = *(const int4*)(p0 + 8);
      a[0] += bflo(u0.x);  a[1] += bfhi(u0.x);
      a[2] += bflo(u0.y);  a[3] += bfhi(u0.y);
      a[4] += bflo(u0.z);  a[5] += bfhi(u0.z);
      a[6] += bflo(u0.w);  a[7] += bfhi(u0.w);
      a[8] += bflo(u1.x);  a[9] += bfhi(u1.x);
      a[10] += bflo(u1.y); a[11] += bfhi(u1.y);
      a[12] += bflo(u1.z); a[13] += bfhi(u1.z);
      a[14] += bflo(u1.w); a[15] += bfhi(u1.w);
    }
#pragma unroll
    for (int d = 0; d < 16; ++d) {
      a[d] += __shfl_xor(a[d], 16);
      a[d] += __shfl_xor(a[d], 32);
    }
    if (quad == 0) {
      ushort* op = agg + (size_t)node * DIN + sub * 16;
      int4 o0, o1;
      o0.x = packbf(a[0] * s, a[1] * s);
      o0.y = packbf(a[2] * s, a[3] * s);
      o0.z = packbf(a[4] * s, a[5] * s);
      o0.w = packbf(a[6] * s, a[7] * s);
      o1.x = packbf(a[8] * s, a[9] * s);
      o1.y = packbf(a[10] * s, a[11] * s);
      o1.z = packbf(a[12] * s, a[13] * s);
      o1.w = packbf(a[14] * s, a[15] * s);
      *(int4*)op = o0;
      *(int4*)(op + 8) = o1;
    }
  } else {  // DIN == 128
    const ushort* base = h + sub * 8;
    float a[8] = {};
    int j = beg + quad;
    for (; j + 4 < end; j += 8) {
      int4 v0 = *(const int4*)(base + (size_t)col[j] * DIN);
      int4 v1 = *(const int4*)(base + (size_t)col[j + 4] * DIN);
      a[0] += bflo(v0.x) + bflo(v1.x);
      a[1] += bfhi(v0.x) + bfhi(v1.x);
      a[2] += bflo(v0.y) + bflo(v1.y);
      a[3] += bfhi(v0.y) + bfhi(v1.y);
      a[4] += bflo(v0.z) + bflo(v1.z);
      a[5] += bfhi(v0.z) + bfhi(v1.z);
      a[6] += bflo(v0.w) + bflo(v1.w);
      a[7] += bfhi(v0.w) + bfhi(v1.w);
    }
    for (; j < end; j += 4) {
      int4 v = *(const int4*)(base + (size_t)col[j] * DIN);
      a[0] += bflo(v.x); a[1] += bfhi(v.x);
      a[2] += bflo(v.y); a[3] += bfhi(v.y);
      a[4] += bflo(v.z); a[5] += bfhi(v.z);
      a[6] += bflo(v.w); a[7] += bfhi(v.w);
    }
#pragma unroll
    for (int d = 0; d < 8; ++d) {
      a[d] += __shfl_xor(a[d], 16);
      a[d] += __shfl_xor(a[d], 32);
    }
    if (quad == 0) {
      int4 o;
      o.x = packbf(a[0] * s, a[1] * s);
      o.y = packbf(a[2] * s, a[3] * s);
      o.z = packbf(a[4] * s, a[5] * s);
      o.w = packbf(a[6] * s, a[7] * s);
      *(int4*)(agg + (size_t)node * DIN + sub * 8) = o;
    }
  }
}

// ---------------- fused GEMM + bias + LayerNorm + ELU (+scaled readout) -----
// R17 body + T5 setprio around MFMA cluster; readout partials pre-scaled by
// 1/gcnt[g] so k_hg_scale is eliminated.
template <int DIN, bool BF16OUT, bool READOUT>
__global__ __launch_bounds__(512) void k_gemm_ln(
    const ushort* __restrict__ A0, const ushort* __restrict__ A1,
    const ushort* __restrict__ Wt, const float* __restrict__ bias,
    const float* __restrict__ g, const float* __restrict__ be,
    ushort* __restrict__ outB, float* __restrict__ outF, int n,
    float* __restrict__ out_hg, const int* __restrict__ gcnt, int npg, int G) {
  constexpr int K = 2 * DIN;
  constexpr int NT = K / 32;
  __shared__ ushort As[3][128 * 32];
  __shared__ ushort Bs[3][256 * 32];
  __shared__ float redS[4][128];
  __shared__ float redQ[4][128];
  __shared__ float hgp[2][256];
  const int tid = threadIdx.x;
  const int lane = tid & 63, wid = tid >> 6;
  const int wr = wid >> 2, wc = wid & 3;
  const int m0 = xcd_swizzle(blockIdx.x, gridDim.x) * 128;
  const int fr = lane & 15, kg = lane >> 4;
  const int srow = wid * 16 + (lane >> 2);
  const int lc = (lane & 3) ^ ((lane >> 3) & 3);  // pre-swizzled source chunk
  const int arow = min(m0 + srow, n - 1);         // clamp; junk rows discarded

  f32x4 acc[4][4] = {};

  auto stage = [&](int buf, int t) {
    int k0 = t * 32;
    const ushort* Asrc = (k0 < DIN) ? A0 : A1;
    int ak = (k0 < DIN) ? k0 : (k0 - DIN);
    gload_lds16(Asrc + (size_t)arow * DIN + ak + lc * 8, &As[buf][wid * 512]);
    gload_lds16(Wt + (size_t)srow * K + k0 + lc * 8, &Bs[buf][wid * 512]);
    gload_lds16(Wt + (size_t)(srow + 128) * K + k0 + lc * 8,
                &Bs[buf][4096 + wid * 512]);
  };

  stage(0, 0);
  if (NT > 1) stage(1, 1);
  if (NT > 2) stage(2, 2);
  int cur = 0;
  for (int t = 0; t < NT; ++t) {
    if (t + 2 < NT) {
      asm volatile("s_waitcnt vmcnt(6)" ::: "memory");  // t landed; t+1,t+2 fly
    } else if (t + 1 < NT) {
      asm volatile("s_waitcnt vmcnt(3)" ::: "memory");
    } else {
      asm volatile("s_waitcnt vmcnt(0)" ::: "memory");
    }
    __builtin_amdgcn_s_barrier();
    __builtin_amdgcn_sched_barrier(0);
    bf16x8 af[4], bb[4];
#pragma unroll
    for (int mi = 0; mi < 4; ++mi) {
      int row = wr * 64 + mi * 16 + fr;
      af[mi] = *(const bf16x8*)&As[cur][row * 32 + ((kg ^ ((row >> 1) & 3)) * 8)];
    }
#pragma unroll
    for (int ni = 0; ni < 4; ++ni) {
      int row = wc * 64 + ni * 16 + fr;
      bb[ni] = *(const bf16x8*)&Bs[cur][row * 32 + ((kg ^ ((row >> 1) & 3)) * 8)];
    }
    __builtin_amdgcn_s_setprio(1);  // T5: favor MFMA-issuing wave
#pragma unroll
    for (int mi = 0; mi < 4; ++mi)
#pragma unroll
      for (int ni = 0; ni < 4; ++ni)
        acc[mi][ni] = __builtin_amdgcn_mfma_f32_16x16x32_bf16(af[mi], bb[ni],
                                                              acc[mi][ni], 0, 0, 0);
    __builtin_amdgcn_s_setprio(0);
    __builtin_amdgcn_sched_barrier(0);
    __builtin_amdgcn_s_barrier();  // reads of [cur] done; buffer free
    if (t + 3 < NT) stage(cur, t + 3);
    cur = (cur == 2) ? 0 : cur + 1;
  }

  float bv[4], gv[4], ev[4];
#pragma unroll
  for (int ni = 0; ni < 4; ++ni) {
    int c = wc * 64 + ni * 16 + fr;
    bv[ni] = bias[c];
    gv[ni] = g[c];
    ev[ni] = be[c];
  }
#pragma unroll
  for (int mi = 0; mi < 4; ++mi)
#pragma unroll
    for (int ni = 0; ni < 4; ++ni)
#pragma unroll
      for (int j = 0; j < 4; ++j) acc[mi][ni][j] += bv[ni];

#pragma unroll
  for (int mi = 0; mi < 4; ++mi) {
#pragma unroll
    for (int j = 0; j < 4; ++j) {
      float s = 0.f, q = 0.f;
#pragma unroll
      for (int ni = 0; ni < 4; ++ni) {
        float a = acc[mi][ni][j];
        s += a;
        q += a * a;
      }
#pragma unroll
      for (int o = 1; o < 16; o <<= 1) {
        s += __shfl_xor(s, o);
        q += __shfl_xor(q, o);
      }
      if (fr == 0) {
        int lr = wr * 64 + mi * 16 + kg * 4 + j;
        redS[wc][lr] = s;
        redQ[wc][lr] = q;
      }
    }
  }
  if constexpr (READOUT) ((float*)hgp)[tid < 512 ? tid : 0] = 0.f;
  __syncthreads();

  const int g0 = m0 / npg;
  const int b1 = (g0 + 1) * npg;
  float s0[4] = {}, s1[4] = {};
#pragma unroll
  for (int mi = 0; mi < 4; ++mi) {
#pragma unroll
    for (int j = 0; j < 4; ++j) {
      int lr = wr * 64 + mi * 16 + kg * 4 + j;
      int r = m0 + lr;
      if (r >= n) continue;
      float tot = redS[0][lr] + redS[1][lr] + redS[2][lr] + redS[3][lr];
      float tq = redQ[0][lr] + redQ[1][lr] + redQ[2][lr] + redQ[3][lr];
      float mean = tot * (1.0f / 256.0f);
      float var = tq * (1.0f / 256.0f) - mean * mean;
      float rstd = rsqrtf(var + 1e-5f);
#pragma unroll
      for (int ni = 0; ni < 4; ++ni) {
        int c = wc * 64 + ni * 16 + fr;
        float val = (acc[mi][ni][j] - mean) * rstd * gv[ni] + ev[ni];
        val = val > 0.f ? val : (__expf(val) - 1.0f);  // cheap ELU (3 ops)
        if constexpr (BF16OUT)
          outB[(size_t)r * DOUT + c] = f2bf(val);
        else
          outF[(size_t)r * DOUT + c] = val;
        if constexpr (READOUT) {
          if (r < b1) s0[ni] += val; else s1[ni] += val;
        }
      }
    }
  }
  if constexpr (READOUT) {
#pragma unroll
    for (int ni = 0; ni < 4; ++ni) {
      int c = wc * 64 + ni * 16 + fr;
      if (s0[ni] != 0.f) atomicAdd(&hgp[0][c], s0[ni]);
      if (s1[ni] != 0.f) atomicAdd(&hgp[1][c], s1[ni]);
    }
    __syncthreads();
    // pre-scaled by 1/cnt: sum over blocks of (partial/cnt) = mean
    if (tid < 256) {
      float v = hgp[0][tid];
      if (v != 0.f)
        atomicAdd(&out_hg[(size_t)g0 * DOUT + tid],
                  v * (1.0f / (float)gcnt[g0]));
    } else {
      float v = hgp[1][tid - 256];
      if (v != 0.f && g0 + 1 < G)
        atomicAdd(&out_hg[(size_t)(g0 + 1) * DOUT + (tid - 256)],
                  v * (1.0f / (float)gcnt[g0 + 1]));
    }
  }
}

extern "C" void kernel_launch(void* const* d_in, const int* in_sizes, int n_in,
                              void* d_out, int out_size, void* d_ws, size_t ws_size,
                              hipStream_t stream) {
  const float* feat = (const float*)d_in[0];
  const int* esrc = (const int*)d_in[1];
  const int* edst = (const int*)d_in[2];
  const int* gid = (const int*)d_in[3];
  const float* Ws0 = (const float*)d_in[4];
  const float* Wn0 = (const float*)d_in[5];
  const float* b0 = (const float*)d_in[6];
  const float* g0 = (const float*)d_in[7];
  const float* be0 = (const float*)d_in[8];
  const float* Ws1 = (const float*)d_in[9];
  const float* Wn1 = (const float*)d_in[10];
  const float* b1 = (const float*)d_in[11];
  const float* g1 = (const float*)d_in[12];
  const float* be1 = (const float*)d_in[13];
  const float* Ws2 = (const float*)d_in[14];
  const float* Wn2 = (const float*)d_in[15];
  const float* b2 = (const float*)d_in[16];
  const float* g2 = (const float*)d_in[17];
  const float* be2 = (const float*)d_in[18];

  const int E = in_sizes[1];
  const int n = in_sizes[3];
  const int DIN0 = in_sizes[0] / n;             // 128
  const int Gn = (out_size - n * DOUT) / DOUT;  // 16
  const int npg = n / Gn;                       // 3125
  const int nb = (n + 255) / 256;
  const int Eb = (E + 255) / 256;

  char* ws = (char*)d_ws;
  size_t off = 0;
  auto alloc = [&](size_t bytes) -> void* {
    void* p = ws + off;
    off += (bytes + 255) & ~(size_t)255;
    return p;
  };
  int* deg_cnt = (int*)alloc((size_t)n * 4);
  int* gcnt = (int*)alloc((size_t)Gn * 4);
  size_t cnt_span = off;
  float* dinv = (float*)alloc((size_t)n * 4);
  int* row_ptr = (int*)alloc((size_t)(n + 1) * 4);
  int* cursor = (int*)alloc((size_t)n * 4);
  int* part = (int*)alloc((size_t)nb * 4);
  int* col = (int*)alloc((size_t)E * 4);
  ushort* feat_bf = (ushort*)alloc((size_t)n * DIN0 * 2);
  ushort* h_bf = (ushort*)alloc((size_t)n * DOUT * 2);
  ushort* agg_bf = (ushort*)alloc((size_t)n * DOUT * 2);
  ushort* Wt0 = (ushort*)alloc((size_t)256 * 2 * DIN0 * 2);
  ushort* Wt1 = (ushort*)alloc((size_t)256 * 2 * DOUT * 2);
  ushort* Wt2 = (ushort*)alloc((size_t)256 * 2 * DOUT * 2);

  float* out_h = (float*)d_out;
  float* out_hg = out_h + (size_t)n * DOUT;

  hipMemsetAsync(deg_cnt, 0, cnt_span, stream);

  k_cnt<<<Eb + nb + 1, 256, 0, stream>>>(edst, deg_cnt, E, Eb, gid, gcnt, n,
                                         Gn, out_hg, nb);

  k_scan1<<<nb, 256, 0, stream>>>(deg_cnt, part, n);
  k_scan2<<<1, 256, 0, stream>>>(part, nb);
  k_scan3<<<nb, 256, 0, stream>>>(deg_cnt, part, row_ptr, cursor, dinv, n);
  k_fill<<<Eb, 256, 0, stream>>>(esrc, edst, cursor, col, E);

  const long long feat4 = (long long)n * DIN0 / 4;
  const int castb = (int)((feat4 + 255) / 256);
  k_prep<<<castb + 2 * DIN0 + 1024, 256, 0, stream>>>(
      feat, feat_bf, feat4, castb, Ws0, Wn0, Wt0, DIN0, Ws1, Wn1, Wt1, Ws2,
      Wn2, Wt2);

  int gemm_grid = (n + 127) / 128;
  int row_grid = (n + 3) / 4;

  // ---- layer 0 ----
  k_gather<128><<<row_grid, 256, 0, stream>>>(feat_bf, row_ptr, col, dinv,
                                              agg_bf, n);
  k_gemm_ln<128, true, false><<<gemm_grid, 512, 0, stream>>>(
      feat_bf, agg_bf, Wt0, b0, g0, be0, h_bf, nullptr, n, nullptr, nullptr,
      npg, Gn);

  // ---- layer 1 (h_bf in place) ----
  k_gather<256><<<row_grid, 256, 0, stream>>>(h_bf, row_ptr, col, dinv,
                                              agg_bf, n);
  k_gemm_ln<256, true, false><<<gemm_grid, 512, 0, stream>>>(
      h_bf, agg_bf, Wt1, b1, g1, be1, h_bf, nullptr, n, nullptr, nullptr,
      npg, Gn);

  // ---- layer 2 -> d_out fp32, scaled readout fused ----
  k_gather<256><<<row_grid, 256, 0, stream>>>(h_bf, row_ptr, col, dinv,
                                              agg_bf, n);
  k_gemm_ln<256, false, true><<<gemm_grid, 512, 0, stream>>>(
      h_bf, agg_bf, Wt2, b2, g2, be2, nullptr, out_h, n, out_hg, gcnt,
      npg, Gn);
}

// Round 19
// 247.710 us; speedup vs baseline: 1.0464x; 1.0464x over previous
//
#include <hip/hip_runtime.h>
#include <hip/hip_bf16.h>

constexpr int DOUT = 256;

typedef __bf16 bf16x8 __attribute__((ext_vector_type(8)));
typedef float f32x4 __attribute__((ext_vector_type(4)));

__device__ inline float bf2f(ushort u) {
  return __uint_as_float((unsigned)u << 16);
}
__device__ inline ushort f2bf(float f) {
  unsigned b = __float_as_uint(f);
  return (ushort)((b + 0x7FFF + ((b >> 16) & 1)) >> 16);  // RNE
}
__device__ inline float bflo(int v) {
  return __uint_as_float((unsigned)v << 16);
}
__device__ inline float bfhi(int v) {
  return __uint_as_float((unsigned)v & 0xffff0000u);
}
__device__ inline int packbf(float a, float b) {
  return (int)((unsigned)f2bf(a) | ((unsigned)f2bf(b) << 16));
}

// async global->LDS, 16B/lane; LDS dest = wave-uniform base + lane*16
__device__ inline void gload_lds16(const ushort* g, ushort* l) {
  __builtin_amdgcn_global_load_lds(
      (const __attribute__((address_space(1))) unsigned int*)g,
      (__attribute__((address_space(3))) unsigned int*)l, 16, 0, 0);
}

// bijective XCD chunk swizzle (m204)
__device__ inline int xcd_swizzle(int bid, int nwg) {
  int q = nwg >> 3, r = nwg & 7;
  int xcd = bid & 7, idx = bid >> 3;
  return (xcd < r ? xcd * (q + 1) : r * (q + 1) + (xcd - r) * q) + idx;
}

// ---- fused counts: [0,Eb) degree, [Eb,Eb+nb) graph histogram, [..+1) hg=0 --
__global__ __launch_bounds__(256) void k_cnt(const int* __restrict__ edst,
                                             int* __restrict__ deg, int E, int Eb,
                                             const int* __restrict__ gid,
                                             int* __restrict__ gcnt, int n, int G,
                                             float* __restrict__ out_hg, int nb) {
  __shared__ int h[16];
  int b = blockIdx.x;
  if (b < Eb) {
    int t = b * 256 + threadIdx.x;
    if (t < E) atomicAdd(&deg[edst[t]], 1);
  } else if (b < Eb + nb) {
    b -= Eb;
    int t = threadIdx.x;
    if (t < G) h[t] = 0;
    __syncthreads();
    int i = b * 256 + t;
    if (i < n) atomicAdd(&h[gid[i]], 1);
    __syncthreads();
    if (t < G && h[t]) atomicAdd(&gcnt[t], h[t]);
  } else {
    int t = threadIdx.x;
    for (int i = t; i < G * 256; i += 256) out_hg[i] = 0.f;
  }
}

// ---------------- CSR build ----------------
__global__ __launch_bounds__(256) void k_scan1(const int* __restrict__ deg,
                                               int* __restrict__ part, int n) {
  int i = blockIdx.x * 256 + threadIdx.x;
  int v = (i < n) ? deg[i] : 0;
#pragma unroll
  for (int o = 32; o > 0; o >>= 1) v += __shfl_xor(v, o);
  __shared__ int s[4];
  int wave = threadIdx.x >> 6, lane = threadIdx.x & 63;
  if (lane == 0) s[wave] = v;
  __syncthreads();
  if (threadIdx.x == 0) part[blockIdx.x] = s[0] + s[1] + s[2] + s[3];
}

__global__ __launch_bounds__(256) void k_scan2(int* __restrict__ part, int nb) {
  __shared__ int s[256];
  int t = threadIdx.x;
  int v = (t < nb) ? part[t] : 0;
  s[t] = v;
  __syncthreads();
  for (int o = 1; o < 256; o <<= 1) {
    int u = (t >= o) ? s[t - o] : 0;
    __syncthreads();
    s[t] += u;
    __syncthreads();
  }
  int excl = (t == 0) ? 0 : s[t - 1];
  if (t < nb) part[t] = excl;
}

__global__ __launch_bounds__(256) void k_scan3(const int* __restrict__ deg,
                                               const int* __restrict__ part,
                                               int* __restrict__ rp,
                                               int* __restrict__ cur,
                                               float* __restrict__ dinv, int n) {
  __shared__ int s[256];
  int t = threadIdx.x;
  int i = blockIdx.x * 256 + t;
  int v = (i < n) ? deg[i] : 0;
  s[t] = v;
  __syncthreads();
  for (int o = 1; o < 256; o <<= 1) {
    int u = (t >= o) ? s[t - o] : 0;
    __syncthreads();
    s[t] += u;
    __syncthreads();
  }
  int incl = s[t];
  int excl = incl - v;
  int base = part[blockIdx.x];
  if (i < n) {
    rp[i] = base + excl;
    cur[i] = base + excl;
    dinv[i] = 1.0f / (float)v;
  }
  if (i == n - 1) rp[n] = base + incl;
}

__global__ __launch_bounds__(256) void k_fill(const int* __restrict__ src,
                                              const int* __restrict__ dst,
                                              int* __restrict__ cur,
                                              int* __restrict__ col, int E) {
  int e = blockIdx.x * 256 + threadIdx.x;
  if (e < E) {
    int p = atomicAdd(&cur[dst[e]], 1);
    col[p] = src[e];
  }
}

// ---------------- fused prep: feat cast + 3 weight transposes ----------------
__global__ __launch_bounds__(256) void k_prep(
    const float* __restrict__ feat, ushort* __restrict__ feat_bf,
    long long feat4, int castb,
    const float* __restrict__ Ws0, const float* __restrict__ Wn0,
    ushort* __restrict__ Wt0, int DIN0,
    const float* __restrict__ Ws1, const float* __restrict__ Wn1,
    ushort* __restrict__ Wt1,
    const float* __restrict__ Ws2, const float* __restrict__ Wn2,
    ushort* __restrict__ Wt2) {
  int b = blockIdx.x;
  if (b < castb) {
    long long t = (long long)b * 256 + threadIdx.x;
    if (t < feat4) {
      float4 v = *(const float4*)(feat + t * 4);
      ushort4 o;
      o.x = f2bf(v.x); o.y = f2bf(v.y); o.z = f2bf(v.z); o.w = f2bf(v.w);
      *(ushort4*)(feat_bf + t * 4) = o;
    }
    return;
  }
  b -= castb;
  const float *Ws, *Wn;
  ushort* Wt;
  int DIN;
  if (b < 2 * DIN0) {
    Ws = Ws0; Wn = Wn0; Wt = Wt0; DIN = DIN0;
  } else if (b < 2 * DIN0 + 512) {
    b -= 2 * DIN0; Ws = Ws1; Wn = Wn1; Wt = Wt1; DIN = 256;
  } else {
    b -= 2 * DIN0 + 512; Ws = Ws2; Wn = Wn2; Wt = Wt2; DIN = 256;
  }
  int t = b * 256 + threadIdx.x;
  int K = 2 * DIN;
  int nn = t & 255;
  int k = t >> 8;
  if (k < K) {
    const float* W = (k < DIN) ? (Ws + (size_t)k * 256)
                               : (Wn + (size_t)(k - DIN) * 256);
    Wt[(size_t)nn * K + k] = f2bf(W[nn]);
  }
}

// ---------------- CSR gather (bf16), 4 neighbor-groups per wave (R15) -------
template <int DIN>
__global__ __launch_bounds__(256) void k_gather(const ushort* __restrict__ h,
                                                const int* __restrict__ rp,
                                                const int* __restrict__ col,
                                                const float* __restrict__ dinv,
                                                ushort* __restrict__ agg, int n) {
  int wg = xcd_swizzle(blockIdx.x, gridDim.x);
  int wave = threadIdx.x >> 6, lane = threadIdx.x & 63;
  int node = wg * 4 + wave;
  if (node >= n) return;
  int beg = rp[node], end = rp[node + 1];
  float s = dinv[node];
  int quad = lane >> 4, sub = lane & 15;
  if constexpr (DIN == 256) {
    const ushort* base = h + sub * 16;
    float a[16] = {};
    int j = beg + quad;
    for (; j + 4 < end; j += 8) {
      const ushort* p0 = base + (size_t)col[j] * DIN;
      const ushort* p1 = base + (size_t)col[j + 4] * DIN;
      int4 u0 = *(const int4*)p0;
      int4 u1 = *(const int4*)(p0 + 8);
      int4 v0 = *(const int4*)p1;
      int4 v1 = *(const int4*)(p1 + 8);
      a[0] += bflo(u0.x) + bflo(v0.x);  a[1] += bfhi(u0.x) + bfhi(v0.x);
      a[2] += bflo(u0.y) + bflo(v0.y);  a[3] += bfhi(u0.y) + bfhi(v0.y);
      a[4] += bflo(u0.z) + bflo(v0.z);  a[5] += bfhi(u0.z) + bfhi(v0.z);
      a[6] += bflo(u0.w) + bflo(v0.w);  a[7] += bfhi(u0.w) + bfhi(v0.w);
      a[8] += bflo(u1.x) + bflo(v1.x);  a[9] += bfhi(u1.x) + bfhi(v1.x);
      a[10] += bflo(u1.y) + bflo(v1.y); a[11] += bfhi(u1.y) + bfhi(v1.y);
      a[12] += bflo(u1.z) + bflo(v1.z); a[13] += bfhi(u1.z) + bfhi(v1.z);
      a[14] += bflo(u1.w) + bflo(v1.w); a[15] += bfhi(u1.w) + bfhi(v1.w);
    }
    for (; j < end; j += 4) {
      const ushort* p0 = base + (size_t)col[j] * DIN;
      int4 u0 = *(const int4*)p0;
      int4 u1 = *(const int4*)(p0 + 8);
      a[0] += bflo(u0.x);  a[1] += bfhi(u0.x);
      a[2] += bflo(u0.y);  a[3] += bfhi(u0.y);
      a[4] += bflo(u0.z);  a[5] += bfhi(u0.z);
      a[6] += bflo(u0.w);  a[7] += bfhi(u0.w);
      a[8] += bflo(u1.x);  a[9] += bfhi(u1.x);
      a[10] += bflo(u1.y); a[11] += bfhi(u1.y);
      a[12] += bflo(u1.z); a[13] += bfhi(u1.z);
      a[14] += bflo(u1.w); a[15] += bfhi(u1.w);
    }
#pragma unroll
    for (int d = 0; d < 16; ++d) {
      a[d] += __shfl_xor(a[d], 16);
      a[d] += __shfl_xor(a[d], 32);
    }
    if (quad == 0) {
      ushort* op = agg + (size_t)node * DIN + sub * 16;
      int4 o0, o1;
      o0.x = packbf(a[0] * s, a[1] * s);
      o0.y = packbf(a[2] * s, a[3] * s);
      o0.z = packbf(a[4] * s, a[5] * s);
      o0.w = packbf(a[6] * s, a[7] * s);
      o1.x = packbf(a[8] * s, a[9] * s);
      o1.y = packbf(a[10] * s, a[11] * s);
      o1.z = packbf(a[12] * s, a[13] * s);
      o1.w = packbf(a[14] * s, a[15] * s);
      *(int4*)op = o0;
      *(int4*)(op + 8) = o1;
    }
  } else {  // DIN == 128
    const ushort* base = h + sub * 8;
    float a[8] = {};
    int j = beg + quad;
    for (; j + 4 < end; j += 8) {
      int4 v0 = *(const int4*)(base + (size_t)col[j] * DIN);
      int4 v1 = *(const int4*)(base + (size_t)col[j + 4] * DIN);
      a[0] += bflo(v0.x) + bflo(v1.x);
      a[1] += bfhi(v0.x) + bfhi(v1.x);
      a[2] += bflo(v0.y) + bflo(v1.y);
      a[3] += bfhi(v0.y) + bfhi(v1.y);
      a[4] += bflo(v0.z) + bflo(v1.z);
      a[5] += bfhi(v0.z) + bfhi(v1.z);
      a[6] += bflo(v0.w) + bflo(v1.w);
      a[7] += bfhi(v0.w) + bfhi(v1.w);
    }
    for (; j < end; j += 4) {
      int4 v = *(const int4*)(base + (size_t)col[j] * DIN);
      a[0] += bflo(v.x); a[1] += bfhi(v.x);
      a[2] += bflo(v.y); a[3] += bfhi(v.y);
      a[4] += bflo(v.z); a[5] += bfhi(v.z);
      a[6] += bflo(v.w); a[7] += bfhi(v.w);
    }
#pragma unroll
    for (int d = 0; d < 8; ++d) {
      a[d] += __shfl_xor(a[d], 16);
      a[d] += __shfl_xor(a[d], 32);
    }
    if (quad == 0) {
      int4 o;
      o.x = packbf(a[0] * s, a[1] * s);
      o.y = packbf(a[2] * s, a[3] * s);
      o.z = packbf(a[4] * s, a[5] * s);
      o.w = packbf(a[6] * s, a[7] * s);
      *(int4*)(agg + (size_t)node * DIN + sub * 8) = o;
    }
  }
}

// ---------------- fused GEMM + bias + LayerNorm + ELU (+scaled readout) -----
// R17 gemm body (3-deep pipeline, counted vmcnt, cheap ELU, XCD swizzle,
// NO setprio) + readout partials pre-scaled by 1/gcnt[g] (k_hg_scale gone).
template <int DIN, bool BF16OUT, bool READOUT>
__global__ __launch_bounds__(512) void k_gemm_ln(
    const ushort* __restrict__ A0, const ushort* __restrict__ A1,
    const ushort* __restrict__ Wt, const float* __restrict__ bias,
    const float* __restrict__ g, const float* __restrict__ be,
    ushort* __restrict__ outB, float* __restrict__ outF, int n,
    float* __restrict__ out_hg, const int* __restrict__ gcnt, int npg, int G) {
  constexpr int K = 2 * DIN;
  constexpr int NT = K / 32;
  __shared__ ushort As[3][128 * 32];
  __shared__ ushort Bs[3][256 * 32];
  __shared__ float redS[4][128];
  __shared__ float redQ[4][128];
  __shared__ float hgp[2][256];
  const int tid = threadIdx.x;
  const int lane = tid & 63, wid = tid >> 6;
  const int wr = wid >> 2, wc = wid & 3;
  const int m0 = xcd_swizzle(blockIdx.x, gridDim.x) * 128;
  const int fr = lane & 15, kg = lane >> 4;
  const int srow = wid * 16 + (lane >> 2);
  const int lc = (lane & 3) ^ ((lane >> 3) & 3);  // pre-swizzled source chunk
  const int arow = min(m0 + srow, n - 1);         // clamp; junk rows discarded

  f32x4 acc[4][4] = {};

  auto stage = [&](int buf, int t) {
    int k0 = t * 32;
    const ushort* Asrc = (k0 < DIN) ? A0 : A1;
    int ak = (k0 < DIN) ? k0 : (k0 - DIN);
    gload_lds16(Asrc + (size_t)arow * DIN + ak + lc * 8, &As[buf][wid * 512]);
    gload_lds16(Wt + (size_t)srow * K + k0 + lc * 8, &Bs[buf][wid * 512]);
    gload_lds16(Wt + (size_t)(srow + 128) * K + k0 + lc * 8,
                &Bs[buf][4096 + wid * 512]);
  };

  stage(0, 0);
  if (NT > 1) stage(1, 1);
  if (NT > 2) stage(2, 2);
  int cur = 0;
  for (int t = 0; t < NT; ++t) {
    if (t + 2 < NT) {
      asm volatile("s_waitcnt vmcnt(6)" ::: "memory");  // t landed; t+1,t+2 fly
    } else if (t + 1 < NT) {
      asm volatile("s_waitcnt vmcnt(3)" ::: "memory");
    } else {
      asm volatile("s_waitcnt vmcnt(0)" ::: "memory");
    }
    __builtin_amdgcn_s_barrier();
    __builtin_amdgcn_sched_barrier(0);
    bf16x8 af[4], bb[4];
#pragma unroll
    for (int mi = 0; mi < 4; ++mi) {
      int row = wr * 64 + mi * 16 + fr;
      af[mi] = *(const bf16x8*)&As[cur][row * 32 + ((kg ^ ((row >> 1) & 3)) * 8)];
    }
#pragma unroll
    for (int ni = 0; ni < 4; ++ni) {
      int row = wc * 64 + ni * 16 + fr;
      bb[ni] = *(const bf16x8*)&Bs[cur][row * 32 + ((kg ^ ((row >> 1) & 3)) * 8)];
    }
#pragma unroll
    for (int mi = 0; mi < 4; ++mi)
#pragma unroll
      for (int ni = 0; ni < 4; ++ni)
        acc[mi][ni] = __builtin_amdgcn_mfma_f32_16x16x32_bf16(af[mi], bb[ni],
                                                              acc[mi][ni], 0, 0, 0);
    __builtin_amdgcn_sched_barrier(0);
    __builtin_amdgcn_s_barrier();  // reads of [cur] done; buffer free
    if (t + 3 < NT) stage(cur, t + 3);
    cur = (cur == 2) ? 0 : cur + 1;
  }

  float bv[4], gv[4], ev[4];
#pragma unroll
  for (int ni = 0; ni < 4; ++ni) {
    int c = wc * 64 + ni * 16 + fr;
    bv[ni] = bias[c];
    gv[ni] = g[c];
    ev[ni] = be[c];
  }
#pragma unroll
  for (int mi = 0; mi < 4; ++mi)
#pragma unroll
    for (int ni = 0; ni < 4; ++ni)
#pragma unroll
      for (int j = 0; j < 4; ++j) acc[mi][ni][j] += bv[ni];

#pragma unroll
  for (int mi = 0; mi < 4; ++mi) {
#pragma unroll
    for (int j = 0; j < 4; ++j) {
      float s = 0.f, q = 0.f;
#pragma unroll
      for (int ni = 0; ni < 4; ++ni) {
        float a = acc[mi][ni][j];
        s += a;
        q += a * a;
      }
#pragma unroll
      for (int o = 1; o < 16; o <<= 1) {
        s += __shfl_xor(s, o);
        q += __shfl_xor(q, o);
      }
      if (fr == 0) {
        int lr = wr * 64 + mi * 16 + kg * 4 + j;
        redS[wc][lr] = s;
        redQ[wc][lr] = q;
      }
    }
  }
  if constexpr (READOUT) ((float*)hgp)[tid < 512 ? tid : 0] = 0.f;
  __syncthreads();

  const int g0 = m0 / npg;
  const int b1 = (g0 + 1) * npg;
  float s0[4] = {}, s1[4] = {};
#pragma unroll
  for (int mi = 0; mi < 4; ++mi) {
#pragma unroll
    for (int j = 0; j < 4; ++j) {
      int lr = wr * 64 + mi * 16 + kg * 4 + j;
      int r = m0 + lr;
      if (r >= n) continue;
      float tot = redS[0][lr] + redS[1][lr] + redS[2][lr] + redS[3][lr];
      float tq = redQ[0][lr] + redQ[1][lr] + redQ[2][lr] + redQ[3][lr];
      float mean = tot * (1.0f / 256.0f);
      float var = tq * (1.0f / 256.0f) - mean * mean;
      float rstd = rsqrtf(var + 1e-5f);
#pragma unroll
      for (int ni = 0; ni < 4; ++ni) {
        int c = wc * 64 + ni * 16 + fr;
        float val = (acc[mi][ni][j] - mean) * rstd * gv[ni] + ev[ni];
        val = val > 0.f ? val : (__expf(val) - 1.0f);  // cheap ELU (3 ops)
        if constexpr (BF16OUT)
          outB[(size_t)r * DOUT + c] = f2bf(val);
        else
          outF[(size_t)r * DOUT + c] = val;
        if constexpr (READOUT) {
          if (r < b1) s0[ni] += val; else s1[ni] += val;
        }
      }
    }
  }
  if constexpr (READOUT) {
#pragma unroll
    for (int ni = 0; ni < 4; ++ni) {
      int c = wc * 64 + ni * 16 + fr;
      if (s0[ni] != 0.f) atomicAdd(&hgp[0][c], s0[ni]);
      if (s1[ni] != 0.f) atomicAdd(&hgp[1][c], s1[ni]);
    }
    __syncthreads();
    // pre-scaled by 1/cnt: sum over blocks of (partial/cnt) = mean
    if (tid < 256) {
      float v = hgp[0][tid];
      if (v != 0.f)
        atomicAdd(&out_hg[(size_t)g0 * DOUT + tid],
                  v * (1.0f / (float)gcnt[g0]));
    } else {
      float v = hgp[1][tid - 256];
      if (v != 0.f && g0 + 1 < G)
        atomicAdd(&out_hg[(size_t)(g0 + 1) * DOUT + (tid - 256)],
                  v * (1.0f / (float)gcnt[g0 + 1]));
    }
  }
}

extern "C" void kernel_launch(void* const* d_in, const int* in_sizes, int n_in,
                              void* d_out, int out_size, void* d_ws, size_t ws_size,
                              hipStream_t stream) {
  const float* feat = (const float*)d_in[0];
  const int* esrc = (const int*)d_in[1];
  const int* edst = (const int*)d_in[2];
  const int* gid = (const int*)d_in[3];
  const float* Ws0 = (const float*)d_in[4];
  const float* Wn0 = (const float*)d_in[5];
  const float* b0 = (const float*)d_in[6];
  const float* g0 = (const float*)d_in[7];
  const float* be0 = (const float*)d_in[8];
  const float* Ws1 = (const float*)d_in[9];
  const float* Wn1 = (const float*)d_in[10];
  const float* b1 = (const float*)d_in[11];
  const float* g1 = (const float*)d_in[12];
  const float* be1 = (const float*)d_in[13];
  const float* Ws2 = (const float*)d_in[14];
  const float* Wn2 = (const float*)d_in[15];
  const float* b2 = (const float*)d_in[16];
  const float* g2 = (const float*)d_in[17];
  const float* be2 = (const float*)d_in[18];

  const int E = in_sizes[1];
  const int n = in_sizes[3];
  const int DIN0 = in_sizes[0] / n;             // 128
  const int Gn = (out_size - n * DOUT) / DOUT;  // 16
  const int npg = n / Gn;                       // 3125
  const int nb = (n + 255) / 256;
  const int Eb = (E + 255) / 256;

  char* ws = (char*)d_ws;
  size_t off = 0;
  auto alloc = [&](size_t bytes) -> void* {
    void* p = ws + off;
    off += (bytes + 255) & ~(size_t)255;
    return p;
  };
  int* deg_cnt = (int*)alloc((size_t)n * 4);
  int* gcnt = (int*)alloc((size_t)Gn * 4);
  size_t cnt_span = off;
  float* dinv = (float*)alloc((size_t)n * 4);
  int* row_ptr = (int*)alloc((size_t)(n + 1) * 4);
  int* cursor = (int*)alloc((size_t)n * 4);
  int* part = (int*)alloc((size_t)nb * 4);
  int* col = (int*)alloc((size_t)E * 4);
  ushort* feat_bf = (ushort*)alloc((size_t)n * DIN0 * 2);
  ushort* h_bf = (ushort*)alloc((size_t)n * DOUT * 2);
  ushort* agg_bf = (ushort*)alloc((size_t)n * DOUT * 2);
  ushort* Wt0 = (ushort*)alloc((size_t)256 * 2 * DIN0 * 2);
  ushort* Wt1 = (ushort*)alloc((size_t)256 * 2 * DOUT * 2);
  ushort* Wt2 = (ushort*)alloc((size_t)256 * 2 * DOUT * 2);

  float* out_h = (float*)d_out;
  float* out_hg = out_h + (size_t)n * DOUT;

  hipMemsetAsync(deg_cnt, 0, cnt_span, stream);

  k_cnt<<<Eb + nb + 1, 256, 0, stream>>>(edst, deg_cnt, E, Eb, gid, gcnt, n,
                                         Gn, out_hg, nb);

  k_scan1<<<nb, 256, 0, stream>>>(deg_cnt, part, n);
  k_scan2<<<1, 256, 0, stream>>>(part, nb);
  k_scan3<<<nb, 256, 0, stream>>>(deg_cnt, part, row_ptr, cursor, dinv, n);
  k_fill<<<Eb, 256, 0, stream>>>(esrc, edst, cursor, col, E);

  const long long feat4 = (long long)n * DIN0 / 4;
  const int castb = (int)((feat4 + 255) / 256);
  k_prep<<<castb + 2 * DIN0 + 1024, 256, 0, stream>>>(
      feat, feat_bf, feat4, castb, Ws0, Wn0, Wt0, DIN0, Ws1, Wn1, Wt1, Ws2,
      Wn2, Wt2);

  int gemm_grid = (n + 127) / 128;
  int row_grid = (n + 3) / 4;

  // ---- layer 0 ----
  k_gather<128><<<row_grid, 256, 0, stream>>>(feat_bf, row_ptr, col, dinv,
                                              agg_bf, n);
  k_gemm_ln<128, true, false><<<gemm_grid, 512, 0, stream>>>(
      feat_bf, agg_bf, Wt0, b0, g0, be0, h_bf, nullptr, n, nullptr, nullptr,
      npg, Gn);

  // ---- layer 1 (h_bf in place) ----
  k_gather<256><<<row_grid, 256, 0, stream>>>(h_bf, row_ptr, col, dinv,
                                              agg_bf, n);
  k_gemm_ln<256, true, false><<<gemm_grid, 512, 0, stream>>>(
      h_bf, agg_bf, Wt1, b1, g1, be1, h_bf, nullptr, n, nullptr, nullptr,
      npg, Gn);

  // ---- layer 2 -> d_out fp32, scaled readout fused ----
  k_gather<256><<<row_grid, 256, 0, stream>>>(h_bf, row_ptr, col, dinv,
                                              agg_bf, n);
  k_gemm_ln<256, false, true><<<gemm_grid, 512, 0, stream>>>(
      h_bf, agg_bf, Wt2, b2, g2, be2, nullptr, out_h, n, out_hg, gcnt,
      npg, Gn);
}

// Round 20
// 244.050 us; speedup vs baseline: 1.0621x; 1.0150x over previous
//
#include <hip/hip_runtime.h>
#include <hip/hip_bf16.h>

constexpr int DOUT = 256;

typedef __bf16 bf16x8 __attribute__((ext_vector_type(8)));
typedef float f32x4 __attribute__((ext_vector_type(4)));

__device__ inline float bf2f(ushort u) {
  return __uint_as_float((unsigned)u << 16);
}
__device__ inline ushort f2bf(float f) {
  unsigned b = __float_as_uint(f);
  return (ushort)((b + 0x7FFF + ((b >> 16) & 1)) >> 16);  // RNE
}
__device__ inline float bflo(int v) {
  return __uint_as_float((unsigned)v << 16);
}
__device__ inline float bfhi(int v) {
  return __uint_as_float((unsigned)v & 0xffff0000u);
}
__device__ inline int packbf(float a, float b) {
  return (int)((unsigned)f2bf(a) | ((unsigned)f2bf(b) << 16));
}

// async global->LDS, 16B/lane; LDS dest = wave-uniform base + lane*16
__device__ inline void gload_lds16(const ushort* g, ushort* l) {
  __builtin_amdgcn_global_load_lds(
      (const __attribute__((address_space(1))) unsigned int*)g,
      (__attribute__((address_space(3))) unsigned int*)l, 16, 0, 0);
}

// bijective XCD chunk swizzle (m204)
__device__ inline int xcd_swizzle(int bid, int nwg) {
  int q = nwg >> 3, r = nwg & 7;
  int xcd = bid & 7, idx = bid >> 3;
  return (xcd < r ? xcd * (q + 1) : r * (q + 1) + (xcd - r) * q) + idx;
}

// ---- fused front kernel: degree count | graph hist | hg-zero | feat cast |
// ---- weight transposes.  All block ranges independent; consumers launch
// ---- after this kernel completes (stream order).
__global__ __launch_bounds__(256) void k_front(
    const int* __restrict__ edst, int* __restrict__ deg, int E, int Eb,
    const int* __restrict__ gid, int* __restrict__ gcnt, int n, int G, int nb,
    float* __restrict__ out_hg,
    const float* __restrict__ feat, ushort* __restrict__ feat_bf,
    long long feat4, int castb,
    const float* __restrict__ Ws0, const float* __restrict__ Wn0,
    ushort* __restrict__ Wt0, int DIN0,
    const float* __restrict__ Ws1, const float* __restrict__ Wn1,
    ushort* __restrict__ Wt1,
    const float* __restrict__ Ws2, const float* __restrict__ Wn2,
    ushort* __restrict__ Wt2) {
  __shared__ int h[16];
  int b = blockIdx.x;
  if (b < Eb) {  // edge degree count (critical path for CSR chain)
    int t = b * 256 + threadIdx.x;
    if (t < E) atomicAdd(&deg[edst[t]], 1);
    return;
  }
  b -= Eb;
  if (b < castb) {  // feat fp32 -> bf16
    long long t = (long long)b * 256 + threadIdx.x;
    if (t < feat4) {
      float4 v = *(const float4*)(feat + t * 4);
      ushort4 o;
      o.x = f2bf(v.x); o.y = f2bf(v.y); o.z = f2bf(v.z); o.w = f2bf(v.w);
      *(ushort4*)(feat_bf + t * 4) = o;
    }
    return;
  }
  b -= castb;
  if (b < nb) {  // per-graph node histogram
    int t = threadIdx.x;
    if (t < G) h[t] = 0;
    __syncthreads();
    int i = b * 256 + t;
    if (i < n) atomicAdd(&h[gid[i]], 1);
    __syncthreads();
    if (t < G && h[t]) atomicAdd(&gcnt[t], h[t]);
    return;
  }
  b -= nb;
  if (b == 0) {  // zero out_hg
    int t = threadIdx.x;
    for (int i = t; i < G * 256; i += 256) out_hg[i] = 0.f;
    return;
  }
  b -= 1;
  // weight transposes: Wt[n][k] bf16
  const float *Ws, *Wn;
  ushort* Wt;
  int DIN;
  if (b < 2 * DIN0) {
    Ws = Ws0; Wn = Wn0; Wt = Wt0; DIN = DIN0;
  } else if (b < 2 * DIN0 + 512) {
    b -= 2 * DIN0; Ws = Ws1; Wn = Wn1; Wt = Wt1; DIN = 256;
  } else {
    b -= 2 * DIN0 + 512; Ws = Ws2; Wn = Wn2; Wt = Wt2; DIN = 256;
  }
  int t = b * 256 + threadIdx.x;
  int K = 2 * DIN;
  int nn = t & 255;
  int k = t >> 8;
  if (k < K) {
    const float* W = (k < DIN) ? (Ws + (size_t)k * 256)
                               : (Wn + (size_t)(k - DIN) * 256);
    Wt[(size_t)nn * K + k] = f2bf(W[nn]);
  }
}

// ---------------- CSR build ----------------
__global__ __launch_bounds__(256) void k_scan1(const int* __restrict__ deg,
                                               int* __restrict__ part, int n) {
  int i = blockIdx.x * 256 + threadIdx.x;
  int v = (i < n) ? deg[i] : 0;
#pragma unroll
  for (int o = 32; o > 0; o >>= 1) v += __shfl_xor(v, o);
  __shared__ int s[4];
  int wave = threadIdx.x >> 6, lane = threadIdx.x & 63;
  if (lane == 0) s[wave] = v;
  __syncthreads();
  if (threadIdx.x == 0) part[blockIdx.x] = s[0] + s[1] + s[2] + s[3];
}

__global__ __launch_bounds__(256) void k_scan2(int* __restrict__ part, int nb) {
  __shared__ int s[256];
  int t = threadIdx.x;
  int v = (t < nb) ? part[t] : 0;
  s[t] = v;
  __syncthreads();
  for (int o = 1; o < 256; o <<= 1) {
    int u = (t >= o) ? s[t - o] : 0;
    __syncthreads();
    s[t] += u;
    __syncthreads();
  }
  int excl = (t == 0) ? 0 : s[t - 1];
  if (t < nb) part[t] = excl;
}

__global__ __launch_bounds__(256) void k_scan3(const int* __restrict__ deg,
                                               const int* __restrict__ part,
                                               int* __restrict__ rp,
                                               int* __restrict__ cur,
                                               float* __restrict__ dinv, int n) {
  __shared__ int s[256];
  int t = threadIdx.x;
  int i = blockIdx.x * 256 + t;
  int v = (i < n) ? deg[i] : 0;
  s[t] = v;
  __syncthreads();
  for (int o = 1; o < 256; o <<= 1) {
    int u = (t >= o) ? s[t - o] : 0;
    __syncthreads();
    s[t] += u;
    __syncthreads();
  }
  int incl = s[t];
  int excl = incl - v;
  int base = part[blockIdx.x];
  if (i < n) {
    rp[i] = base + excl;
    cur[i] = base + excl;
    dinv[i] = 1.0f / (float)v;
  }
  if (i == n - 1) rp[n] = base + incl;
}

__global__ __launch_bounds__(256) void k_fill(const int* __restrict__ src,
                                              const int* __restrict__ dst,
                                              int* __restrict__ cur,
                                              int* __restrict__ col, int E) {
  int e = blockIdx.x * 256 + threadIdx.x;
  if (e < E) {
    int p = atomicAdd(&cur[dst[e]], 1);
    col[p] = src[e];
  }
}

// ---------------- CSR gather (bf16), 4 neighbor-groups per wave (R15) -------
template <int DIN>
__global__ __launch_bounds__(256) void k_gather(const ushort* __restrict__ h,
                                                const int* __restrict__ rp,
                                                const int* __restrict__ col,
                                                const float* __restrict__ dinv,
                                                ushort* __restrict__ agg, int n) {
  int wg = xcd_swizzle(blockIdx.x, gridDim.x);
  int wave = threadIdx.x >> 6, lane = threadIdx.x & 63;
  int node = wg * 4 + wave;
  if (node >= n) return;
  int beg = rp[node], end = rp[node + 1];
  float s = dinv[node];
  int quad = lane >> 4, sub = lane & 15;
  if constexpr (DIN == 256) {
    const ushort* base = h + sub * 16;
    float a[16] = {};
    int j = beg + quad;
    for (; j + 4 < end; j += 8) {
      const ushort* p0 = base + (size_t)col[j] * DIN;
      const ushort* p1 = base + (size_t)col[j + 4] * DIN;
      int4 u0 = *(const int4*)p0;
      int4 u1 = *(const int4*)(p0 + 8);
      int4 v0 = *(const int4*)p1;
      int4 v1 = *(const int4*)(p1 + 8);
      a[0] += bflo(u0.x) + bflo(v0.x);  a[1] += bfhi(u0.x) + bfhi(v0.x);
      a[2] += bflo(u0.y) + bflo(v0.y);  a[3] += bfhi(u0.y) + bfhi(v0.y);
      a[4] += bflo(u0.z) + bflo(v0.z);  a[5] += bfhi(u0.z) + bfhi(v0.z);
      a[6] += bflo(u0.w) + bflo(v0.w);  a[7] += bfhi(u0.w) + bfhi(v0.w);
      a[8] += bflo(u1.x) + bflo(v1.x);  a[9] += bfhi(u1.x) + bfhi(v1.x);
      a[10] += bflo(u1.y) + bflo(v1.y); a[11] += bfhi(u1.y) + bfhi(v1.y);
      a[12] += bflo(u1.z) + bflo(v1.z); a[13] += bfhi(u1.z) + bfhi(v1.z);
      a[14] += bflo(u1.w) + bflo(v1.w); a[15] += bfhi(u1.w) + bfhi(v1.w);
    }
    for (; j < end; j += 4) {
      const ushort* p0 = base + (size_t)col[j] * DIN;
      int4 u0 = *(const int4*)p0;
      int4 u1 = *(const int4*)(p0 + 8);
      a[0] += bflo(u0.x);  a[1] += bfhi(u0.x);
      a[2] += bflo(u0.y);  a[3] += bfhi(u0.y);
      a[4] += bflo(u0.z);  a[5] += bfhi(u0.z);
      a[6] += bflo(u0.w);  a[7] += bfhi(u0.w);
      a[8] += bflo(u1.x);  a[9] += bfhi(u1.x);
      a[10] += bflo(u1.y); a[11] += bfhi(u1.y);
      a[12] += bflo(u1.z); a[13] += bfhi(u1.z);
      a[14] += bflo(u1.w); a[15] += bfhi(u1.w);
    }
#pragma unroll
    for (int d = 0; d < 16; ++d) {
      a[d] += __shfl_xor(a[d], 16);
      a[d] += __shfl_xor(a[d], 32);
    }
    if (quad == 0) {
      ushort* op = agg + (size_t)node * DIN + sub * 16;
      int4 o0, o1;
      o0.x = packbf(a[0] * s, a[1] * s);
      o0.y = packbf(a[2] * s, a[3] * s);
      o0.z = packbf(a[4] * s, a[5] * s);
      o0.w = packbf(a[6] * s, a[7] * s);
      o1.x = packbf(a[8] * s, a[9] * s);
      o1.y = packbf(a[10] * s, a[11] * s);
      o1.z = packbf(a[12] * s, a[13] * s);
      o1.w = packbf(a[14] * s, a[15] * s);
      *(int4*)op = o0;
      *(int4*)(op + 8) = o1;
    }
  } else {  // DIN == 128
    const ushort* base = h + sub * 8;
    float a[8] = {};
    int j = beg + quad;
    for (; j + 4 < end; j += 8) {
      int4 v0 = *(const int4*)(base + (size_t)col[j] * DIN);
      int4 v1 = *(const int4*)(base + (size_t)col[j + 4] * DIN);
      a[0] += bflo(v0.x) + bflo(v1.x);
      a[1] += bfhi(v0.x) + bfhi(v1.x);
      a[2] += bflo(v0.y) + bflo(v1.y);
      a[3] += bfhi(v0.y) + bfhi(v1.y);
      a[4] += bflo(v0.z) + bflo(v1.z);
      a[5] += bfhi(v0.z) + bfhi(v1.z);
      a[6] += bflo(v0.w) + bflo(v1.w);
      a[7] += bfhi(v0.w) + bfhi(v1.w);
    }
    for (; j < end; j += 4) {
      int4 v = *(const int4*)(base + (size_t)col[j] * DIN);
      a[0] += bflo(v.x); a[1] += bfhi(v.x);
      a[2] += bflo(v.y); a[3] += bfhi(v.y);
      a[4] += bflo(v.z); a[5] += bfhi(v.z);
      a[6] += bflo(v.w); a[7] += bfhi(v.w);
    }
#pragma unroll
    for (int d = 0; d < 8; ++d) {
      a[d] += __shfl_xor(a[d], 16);
      a[d] += __shfl_xor(a[d], 32);
    }
    if (quad == 0) {
      int4 o;
      o.x = packbf(a[0] * s, a[1] * s);
      o.y = packbf(a[2] * s, a[3] * s);
      o.z = packbf(a[4] * s, a[5] * s);
      o.w = packbf(a[6] * s, a[7] * s);
      *(int4*)(agg + (size_t)node * DIN + sub * 8) = o;
    }
  }
}

// ---------------- fused GEMM + bias + LayerNorm + ELU (+scaled readout) -----
// R19 gemm body: 3-deep pipeline, counted vmcnt, cheap ELU, XCD swizzle,
// readout partials pre-scaled by 1/gcnt[g].
template <int DIN, bool BF16OUT, bool READOUT>
__global__ __launch_bounds__(512) void k_gemm_ln(
    const ushort* __restrict__ A0, const ushort* __restrict__ A1,
    const ushort* __restrict__ Wt, const float* __restrict__ bias,
    const float* __restrict__ g, const float* __restrict__ be,
    ushort* __restrict__ outB, float* __restrict__ outF, int n,
    float* __restrict__ out_hg, const int* __restrict__ gcnt, int npg, int G) {
  constexpr int K = 2 * DIN;
  constexpr int NT = K / 32;
  __shared__ ushort As[3][128 * 32];
  __shared__ ushort Bs[3][256 * 32];
  __shared__ float redS[4][128];
  __shared__ float redQ[4][128];
  __shared__ float hgp[2][256];
  const int tid = threadIdx.x;
  const int lane = tid & 63, wid = tid >> 6;
  const int wr = wid >> 2, wc = wid & 3;
  const int m0 = xcd_swizzle(blockIdx.x, gridDim.x) * 128;
  const int fr = lane & 15, kg = lane >> 4;
  const int srow = wid * 16 + (lane >> 2);
  const int lc = (lane & 3) ^ ((lane >> 3) & 3);  // pre-swizzled source chunk
  const int arow = min(m0 + srow, n - 1);         // clamp; junk rows discarded

  f32x4 acc[4][4] = {};

  auto stage = [&](int buf, int t) {
    int k0 = t * 32;
    const ushort* Asrc = (k0 < DIN) ? A0 : A1;
    int ak = (k0 < DIN) ? k0 : (k0 - DIN);
    gload_lds16(Asrc + (size_t)arow * DIN + ak + lc * 8, &As[buf][wid * 512]);
    gload_lds16(Wt + (size_t)srow * K + k0 + lc * 8, &Bs[buf][wid * 512]);
    gload_lds16(Wt + (size_t)(srow + 128) * K + k0 + lc * 8,
                &Bs[buf][4096 + wid * 512]);
  };

  stage(0, 0);
  if (NT > 1) stage(1, 1);
  if (NT > 2) stage(2, 2);
  int cur = 0;
  for (int t = 0; t < NT; ++t) {
    if (t + 2 < NT) {
      asm volatile("s_waitcnt vmcnt(6)" ::: "memory");  // t landed; t+1,t+2 fly
    } else if (t + 1 < NT) {
      asm volatile("s_waitcnt vmcnt(3)" ::: "memory");
    } else {
      asm volatile("s_waitcnt vmcnt(0)" ::: "memory");
    }
    __builtin_amdgcn_s_barrier();
    __builtin_amdgcn_sched_barrier(0);
    bf16x8 af[4], bb[4];
#pragma unroll
    for (int mi = 0; mi < 4; ++mi) {
      int row = wr * 64 + mi * 16 + fr;
      af[mi] = *(const bf16x8*)&As[cur][row * 32 + ((kg ^ ((row >> 1) & 3)) * 8)];
    }
#pragma unroll
    for (int ni = 0; ni < 4; ++ni) {
      int row = wc * 64 + ni * 16 + fr;
      bb[ni] = *(const bf16x8*)&Bs[cur][row * 32 + ((kg ^ ((row >> 1) & 3)) * 8)];
    }
#pragma unroll
    for (int mi = 0; mi < 4; ++mi)
#pragma unroll
      for (int ni = 0; ni < 4; ++ni)
        acc[mi][ni] = __builtin_amdgcn_mfma_f32_16x16x32_bf16(af[mi], bb[ni],
                                                              acc[mi][ni], 0, 0, 0);
    __builtin_amdgcn_sched_barrier(0);
    __builtin_amdgcn_s_barrier();  // reads of [cur] done; buffer free
    if (t + 3 < NT) stage(cur, t + 3);
    cur = (cur == 2) ? 0 : cur + 1;
  }

  float bv[4], gv[4], ev[4];
#pragma unroll
  for (int ni = 0; ni < 4; ++ni) {
    int c = wc * 64 + ni * 16 + fr;
    bv[ni] = bias[c];
    gv[ni] = g[c];
    ev[ni] = be[c];
  }
#pragma unroll
  for (int mi = 0; mi < 4; ++mi)
#pragma unroll
    for (int ni = 0; ni < 4; ++ni)
#pragma unroll
      for (int j = 0; j < 4; ++j) acc[mi][ni][j] += bv[ni];

#pragma unroll
  for (int mi = 0; mi < 4; ++mi) {
#pragma unroll
    for (int j = 0; j < 4; ++j) {
      float s = 0.f, q = 0.f;
#pragma unroll
      for (int ni = 0; ni < 4; ++ni) {
        float a = acc[mi][ni][j];
        s += a;
        q += a * a;
      }
#pragma unroll
      for (int o = 1; o < 16; o <<= 1) {
        s += __shfl_xor(s, o);
        q += __shfl_xor(q, o);
      }
      if (fr == 0) {
        int lr = wr * 64 + mi * 16 + kg * 4 + j;
        redS[wc][lr] = s;
        redQ[wc][lr] = q;
      }
    }
  }
  if constexpr (READOUT) ((float*)hgp)[tid < 512 ? tid : 0] = 0.f;
  __syncthreads();

  const int g0 = m0 / npg;
  const int b1 = (g0 + 1) * npg;
  float s0[4] = {}, s1[4] = {};
#pragma unroll
  for (int mi = 0; mi < 4; ++mi) {
#pragma unroll
    for (int j = 0; j < 4; ++j) {
      int lr = wr * 64 + mi * 16 + kg * 4 + j;
      int r = m0 + lr;
      if (r >= n) continue;
      float tot = redS[0][lr] + redS[1][lr] + redS[2][lr] + redS[3][lr];
      float tq = redQ[0][lr] + redQ[1][lr] + redQ[2][lr] + redQ[3][lr];
      float mean = tot * (1.0f / 256.0f);
      float var = tq * (1.0f / 256.0f) - mean * mean;
      float rstd = rsqrtf(var + 1e-5f);
#pragma unroll
      for (int ni = 0; ni < 4; ++ni) {
        int c = wc * 64 + ni * 16 + fr;
        float val = (acc[mi][ni][j] - mean) * rstd * gv[ni] + ev[ni];
        val = val > 0.f ? val : (__expf(val) - 1.0f);  // cheap ELU (3 ops)
        if constexpr (BF16OUT)
          outB[(size_t)r * DOUT + c] = f2bf(val);
        else
          outF[(size_t)r * DOUT + c] = val;
        if constexpr (READOUT) {
          if (r < b1) s0[ni] += val; else s1[ni] += val;
        }
      }
    }
  }
  if constexpr (READOUT) {
#pragma unroll
    for (int ni = 0; ni < 4; ++ni) {
      int c = wc * 64 + ni * 16 + fr;
      if (s0[ni] != 0.f) atomicAdd(&hgp[0][c], s0[ni]);
      if (s1[ni] != 0.f) atomicAdd(&hgp[1][c], s1[ni]);
    }
    __syncthreads();
    if (tid < 256) {
      float v = hgp[0][tid];
      if (v != 0.f)
        atomicAdd(&out_hg[(size_t)g0 * DOUT + tid],
                  v * (1.0f / (float)gcnt[g0]));
    } else {
      float v = hgp[1][tid - 256];
      if (v != 0.f && g0 + 1 < G)
        atomicAdd(&out_hg[(size_t)(g0 + 1) * DOUT + (tid - 256)],
                  v * (1.0f / (float)gcnt[g0 + 1]));
    }
  }
}

extern "C" void kernel_launch(void* const* d_in, const int* in_sizes, int n_in,
                              void* d_out, int out_size, void* d_ws, size_t ws_size,
                              hipStream_t stream) {
  const float* feat = (const float*)d_in[0];
  const int* esrc = (const int*)d_in[1];
  const int* edst = (const int*)d_in[2];
  const int* gid = (const int*)d_in[3];
  const float* Ws0 = (const float*)d_in[4];
  const float* Wn0 = (const float*)d_in[5];
  const float* b0 = (const float*)d_in[6];
  const float* g0 = (const float*)d_in[7];
  const float* be0 = (const float*)d_in[8];
  const float* Ws1 = (const float*)d_in[9];
  const float* Wn1 = (const float*)d_in[10];
  const float* b1 = (const float*)d_in[11];
  const float* g1 = (const float*)d_in[12];
  const float* be1 = (const float*)d_in[13];
  const float* Ws2 = (const float*)d_in[14];
  const float* Wn2 = (const float*)d_in[15];
  const float* b2 = (const float*)d_in[16];
  const float* g2 = (const float*)d_in[17];
  const float* be2 = (const float*)d_in[18];

  const int E = in_sizes[1];
  const int n = in_sizes[3];
  const int DIN0 = in_sizes[0] / n;             // 128
  const int Gn = (out_size - n * DOUT) / DOUT;  // 16
  const int npg = n / Gn;                       // 3125
  const int nb = (n + 255) / 256;
  const int Eb = (E + 255) / 256;

  char* ws = (char*)d_ws;
  size_t off = 0;
  auto alloc = [&](size_t bytes) -> void* {
    void* p = ws + off;
    off += (bytes + 255) & ~(size_t)255;
    return p;
  };
  int* deg_cnt = (int*)alloc((size_t)n * 4);
  int* gcnt = (int*)alloc((size_t)Gn * 4);
  size_t cnt_span = off;
  float* dinv = (float*)alloc((size_t)n * 4);
  int* row_ptr = (int*)alloc((size_t)(n + 1) * 4);
  int* cursor = (int*)alloc((size_t)n * 4);
  int* part = (int*)alloc((size_t)nb * 4);
  int* col = (int*)alloc((size_t)E * 4);
  ushort* feat_bf = (ushort*)alloc((size_t)n * DIN0 * 2);
  ushort* h_bf = (ushort*)alloc((size_t)n * DOUT * 2);
  ushort* agg_bf = (ushort*)alloc((size_t)n * DOUT * 2);
  ushort* Wt0 = (ushort*)alloc((size_t)256 * 2 * DIN0 * 2);
  ushort* Wt1 = (ushort*)alloc((size_t)256 * 2 * DOUT * 2);
  ushort* Wt2 = (ushort*)alloc((size_t)256 * 2 * DOUT * 2);

  float* out_h = (float*)d_out;
  float* out_hg = out_h + (size_t)n * DOUT;

  hipMemsetAsync(deg_cnt, 0, cnt_span, stream);

  const long long feat4 = (long long)n * DIN0 / 4;
  const int castb = (int)((feat4 + 255) / 256);
  const int front_grid = Eb + castb + nb + 1 + 2 * DIN0 + 1024;
  k_front<<<front_grid, 256, 0, stream>>>(
      edst, deg_cnt, E, Eb, gid, gcnt, n, Gn, nb, out_hg, feat, feat_bf,
      feat4, castb, Ws0, Wn0, Wt0, DIN0, Ws1, Wn1, Wt1, Ws2, Wn2, Wt2);

  k_scan1<<<nb, 256, 0, stream>>>(deg_cnt, part, n);
  k_scan2<<<1, 256, 0, stream>>>(part, nb);
  k_scan3<<<nb, 256, 0, stream>>>(deg_cnt, part, row_ptr, cursor, dinv, n);
  k_fill<<<Eb, 256, 0, stream>>>(esrc, edst, cursor, col, E);

  int gemm_grid = (n + 127) / 128;
  int row_grid = (n + 3) / 4;

  // ---- layer 0 ----
  k_gather<128><<<row_grid, 256, 0, stream>>>(feat_bf, row_ptr, col, dinv,
                                              agg_bf, n);
  k_gemm_ln<128, true, false><<<gemm_grid, 512, 0, stream>>>(
      feat_bf, agg_bf, Wt0, b0, g0, be0, h_bf, nullptr, n, nullptr, nullptr,
      npg, Gn);

  // ---- layer 1 (h_bf in place) ----
  k_gather<256><<<row_grid, 256, 0, stream>>>(h_bf, row_ptr, col, dinv,
                                              agg_bf, n);
  k_gemm_ln<256, true, false><<<gemm_grid, 512, 0, stream>>>(
      h_bf, agg_bf, Wt1, b1, g1, be1, h_bf, nullptr, n, nullptr, nullptr,
      npg, Gn);

  // ---- layer 2 -> d_out fp32, scaled readout fused ----
  k_gather<256><<<row_grid, 256, 0, stream>>>(h_bf, row_ptr, col, dinv,
                                              agg_bf, n);
  k_gemm_ln<256, false, true><<<gemm_grid, 512, 0, stream>>>(
      h_bf, agg_bf, Wt2, b2, g2, be2, nullptr, out_h, n, out_hg, gcnt,
      npg, Gn);
}